// Round 3
// baseline (50167.651 us; speedup 1.0000x reference)
//
#include <hip/hip_runtime.h>

typedef _Float16 h8 __attribute__((ext_vector_type(8)));
typedef float f4v __attribute__((ext_vector_type(4)));
typedef unsigned short u16;

#define SEQ 2048
#define HID 512
#define EMB 256
#define NV 32000
#define LOSCALE 2048.0f
#define INV_LOSCALE 4.8828125e-4f  // 2^-11

// ---------------------------------------------------------------------------
// K0: split W_hh (fp32 [k=512][j=512]) into f16 hi + f16 lo*2^11, laid out in
// MFMA B-fragment stream order for the 16-wave rnn kernel.
// Fragment c = (w*16+kb)*2+jt (1KB each); within it lane l holds 8 f16:
//   W[kb*32 + (l>>4)*8 + e][w*32 + jt*16 + (l&15)]
// ---------------------------------------------------------------------------
__global__ void wsplit_kernel(const float* __restrict__ Whh,
                              _Float16* __restrict__ Whi,
                              _Float16* __restrict__ Wlo) {
  int gid = blockIdx.x * 256 + threadIdx.x;  // 0..32767
  int l = gid & 63, c = gid >> 6;            // c in [0,512)
  int jt = c & 1, kb = (c >> 1) & 15, w = c >> 5;
  int j = w * 32 + jt * 16 + (l & 15);
  int k0 = kb * 32 + (l >> 4) * 8;
  _Float16 hi[8], lo[8];
#pragma unroll
  for (int e = 0; e < 8; ++e) {
    float v = Whh[(k0 + e) * HID + j];
    _Float16 h = (_Float16)v;
    hi[e] = h;
    lo[e] = (_Float16)((v - (float)h) * LOSCALE);
  }
  *(h8*)(Whi + (size_t)gid * 8) = *(const h8*)hi;
  *(h8*)(Wlo + (size_t)gid * 8) = *(const h8*)lo;
}

// ---------------------------------------------------------------------------
// K1: projE[v][j] = sum_d E[v][d] * W_xh[d][j] + b_xh[j]   (32000 x 512) fp32
// (f16 fallback if workspace is small). Verified-clean structure from R1.
// ---------------------------------------------------------------------------
template <bool PF32>
__global__ __launch_bounds__(256) void proj_kernel(const float* __restrict__ E,
                                                   const float* __restrict__ Wxh,
                                                   const float* __restrict__ bxh,
                                                   void* __restrict__ projE) {
  __shared__ float El[32 * EMB];
  const int t = threadIdx.x;
  const int v0 = blockIdx.x * 32;
  {
    const float4* src = (const float4*)(E + (size_t)v0 * EMB);
    float4* dst = (float4*)El;
#pragma unroll
    for (int i = 0; i < 8; ++i) dst[t + i * 256] = src[t + i * 256];
  }
  __syncthreads();
  const int c0 = (t & 63) * 8;
  const int rg = t >> 6;
  float acc[8][8];
#pragma unroll
  for (int r = 0; r < 8; ++r)
#pragma unroll
    for (int c = 0; c < 8; ++c) acc[r][c] = 0.f;

#pragma unroll 4
  for (int d = 0; d < EMB; ++d) {
    float wv[8];
    *(float4*)&wv[0] = *(const float4*)&Wxh[d * HID + c0];
    *(float4*)&wv[4] = *(const float4*)&Wxh[d * HID + c0 + 4];
#pragma unroll
    for (int r = 0; r < 8; ++r) {
      float ev = El[(rg * 8 + r) * EMB + d];
#pragma unroll
      for (int c = 0; c < 8; ++c) acc[r][c] = fmaf(ev, wv[c], acc[r][c]);
    }
  }
  float bv[8];
  *(float4*)&bv[0] = *(const float4*)&bxh[c0];
  *(float4*)&bv[4] = *(const float4*)&bxh[c0 + 4];
#pragma unroll
  for (int r = 0; r < 8; ++r) {
    int row = v0 + rg * 8 + r;
    if (PF32) {
      float o[8];
#pragma unroll
      for (int c = 0; c < 8; ++c) o[c] = acc[r][c] + bv[c];
      *(float4*)((float*)projE + (size_t)row * HID + c0) = *(const float4*)&o[0];
      *(float4*)((float*)projE + (size_t)row * HID + c0 + 4) = *(const float4*)&o[4];
    } else {
      _Float16 o[8];
#pragma unroll
      for (int c = 0; c < 8; ++c) o[c] = (_Float16)(acc[r][c] + bv[c]);
      *(h8*)((_Float16*)projE + (size_t)row * HID + c0) = *(const h8*)o;
    }
  }
}

// ---------------------------------------------------------------------------
// K2: persistent recurrence, 4 blocks x 1024 threads (16 waves). Block owns
// 16 batch rows (MFMA M=16); wave w owns cols [w*32, w*32+32) (2 J-tiles).
// h kept as f16 hi + f16 lo*2^11 in LDS, double-buffered, XOR-swizzled
// (^(row&7)<<4) against the stride-1024B A-fragment bank conflict.
// 3-term split GEMM: acc1 += hh*Wh ; accC += hh*Wl + hl*Wh ; v = acc1 +
// 2^-11*accC + b + xp. One __syncthreads per step.
// ---------------------------------------------------------------------------
template <bool PF32>
__global__ __launch_bounds__(1024, 4) void rnn_kernel(const int* __restrict__ X,
                                                      const _Float16* __restrict__ Whi,
                                                      const _Float16* __restrict__ Wlo,
                                                      const void* __restrict__ projE,
                                                      const float* __restrict__ bhh,
                                                      float* __restrict__ out) {
  __shared__ __align__(16) char hbuf[2][2][16 * 1024];  // [dbuf][hi/lo][16][512] f16
  const int tid = threadIdx.x;
  const int w = tid >> 6, lane = tid & 63;
  const int g = lane >> 4, li = lane & 15;
  const int nb = blockIdx.x * 16;

  {  // zero-init both buffers (h0 = 0): 64KB = 4096 f4v
    f4v z = {0.f, 0.f, 0.f, 0.f};
    f4v* p = (f4v*)hbuf;
#pragma unroll
    for (int i = 0; i < 4; ++i) p[tid + i * 1024] = z;
  }

  float bias[2];
#pragma unroll
  for (int jt = 0; jt < 2; ++jt) bias[jt] = bhh[w * 32 + jt * 16 + li];

  const char* whbase = (const char*)Whi + (size_t)w * 32768 + (size_t)lane * 16;
  const char* wlbase = (const char*)Wlo + (size_t)w * 32768 + (size_t)lane * 16;

  __syncthreads();

  for (int t = 0; t < SEQ; ++t) {
    const char* hchi = hbuf[t & 1][0];
    const char* hclo = hbuf[t & 1][1];
    char* hnhi = hbuf[(t + 1) & 1][0];
    char* hnlo = hbuf[(t + 1) & 1][1];

    // xp gather for this step (consumed ~7K cycles later in the epilogue)
    float pv[4][2];
#pragma unroll
    for (int i = 0; i < 4; ++i) {
      int tok = X[(nb + g * 4 + i) * SEQ + t];
#pragma unroll
      for (int jt = 0; jt < 2; ++jt) {
        int j = w * 32 + jt * 16 + li;
        if (PF32)
          pv[i][jt] = ((const float*)projE)[(size_t)tok * HID + j];
        else
          pv[i][jt] = (float)((const _Float16*)projE)[(size_t)tok * HID + j];
      }
    }

    f4v a1[2], ac[2];
#pragma unroll
    for (int jt = 0; jt < 2; ++jt) {
      a1[jt] = (f4v){0.f, 0.f, 0.f, 0.f};
      ac[jt] = (f4v){0.f, 0.f, 0.f, 0.f};
    }

    // 3-stage W prefetch from L2 (frag (w,kb,jt) at w*32768 + kb*2048 + jt*1024)
    h8 bh_a[2], bl_a[2], bh_b[2], bl_b[2];
#pragma unroll
    for (int jt = 0; jt < 2; ++jt) {
      bh_a[jt] = *(const h8*)(whbase + jt * 1024);
      bl_a[jt] = *(const h8*)(wlbase + jt * 1024);
      bh_b[jt] = *(const h8*)(whbase + 2048 + jt * 1024);
      bl_b[jt] = *(const h8*)(wlbase + 2048 + jt * 1024);
    }

#pragma unroll
    for (int kb = 0; kb < 16; ++kb) {
      int aoff = (li * 1024 + kb * 64 + g * 16) ^ ((li & 7) << 4);
      h8 ahi = *(const h8*)(hchi + aoff);
      h8 alo = *(const h8*)(hclo + aoff);
      h8 bh[2], bl[2];
#pragma unroll
      for (int jt = 0; jt < 2; ++jt) { bh[jt] = bh_a[jt]; bl[jt] = bl_a[jt]; }
#pragma unroll
      for (int jt = 0; jt < 2; ++jt) { bh_a[jt] = bh_b[jt]; bl_a[jt] = bl_b[jt]; }
      if (kb < 14) {
#pragma unroll
        for (int jt = 0; jt < 2; ++jt) {
          bh_b[jt] = *(const h8*)(whbase + (kb + 2) * 2048 + jt * 1024);
          bl_b[jt] = *(const h8*)(wlbase + (kb + 2) * 2048 + jt * 1024);
        }
      }
#pragma unroll
      for (int jt = 0; jt < 2; ++jt) {
        a1[jt] = __builtin_amdgcn_mfma_f32_16x16x32_f16(ahi, bh[jt], a1[jt], 0, 0, 0);
        ac[jt] = __builtin_amdgcn_mfma_f32_16x16x32_f16(ahi, bl[jt], ac[jt], 0, 0, 0);
        ac[jt] = __builtin_amdgcn_mfma_f32_16x16x32_f16(alo, bh[jt], ac[jt], 0, 0, 0);
      }
    }

    const bool last = (t == SEQ - 1);
#pragma unroll
    for (int jt = 0; jt < 2; ++jt) {
      int j = w * 32 + jt * 16 + li;
#pragma unroll
      for (int i = 0; i < 4; ++i) {
        int m = g * 4 + i;
        float v = a1[jt][i] + INV_LOSCALE * ac[jt][i] + bias[jt] + pv[i][jt];
        float e2 = __expf(2.0f * v);
        float th = 1.0f - 2.0f / (e2 + 1.0f);
        _Float16 hh = (_Float16)th;
        _Float16 hl = (_Float16)((th - (float)hh) * LOSCALE);
        int off = (m * 1024 + j * 2) ^ ((m & 7) << 4);
        *(_Float16*)(hnhi + off) = hh;
        *(_Float16*)(hnlo + off) = hl;
        if (last) out[(nb + m) * HID + j] = th;
      }
    }
    __syncthreads();
  }
}

// ---------------------------------------------------------------------------
extern "C" void kernel_launch(void* const* d_in, const int* in_sizes, int n_in,
                              void* d_out, int out_size, void* d_ws, size_t ws_size,
                              hipStream_t stream) {
  const int* X = (const int*)d_in[0];
  const float* E = (const float*)d_in[1];
  const float* Whh = (const float*)d_in[2];
  const float* bhh = (const float*)d_in[3];
  const float* Wxh = (const float*)d_in[4];
  const float* bxh = (const float*)d_in[5];
  float* out = (float*)d_out;

  char* ws = (char*)d_ws;
  _Float16* Whi = (_Float16*)ws;                       // 512 KB
  _Float16* Wlo = (_Float16*)(ws + 512 * 1024);        // 512 KB
  void* projE = (void*)(ws + 1024 * 1024);             // 65.5 MB fp32 / 32.8 MB f16
  const bool pf32 =
      ws_size >= (size_t)(1024 * 1024) + (size_t)NV * HID * sizeof(float);

  wsplit_kernel<<<128, 256, 0, stream>>>(Whh, Whi, Wlo);
  if (pf32) {
    proj_kernel<true><<<NV / 32, 256, 0, stream>>>(E, Wxh, bxh, projE);
    rnn_kernel<true><<<4, 1024, 0, stream>>>(X, Whi, Wlo, projE, bhh, out);
  } else {
    proj_kernel<false><<<NV / 32, 256, 0, stream>>>(E, Wxh, bxh, projE);
    rnn_kernel<false><<<4, 1024, 0, stream>>>(X, Whi, Wlo, projE, bhh, out);
  }
}

// Round 5
// 20985.902 us; speedup vs baseline: 2.3905x; 2.3905x over previous
//
#include <hip/hip_runtime.h>

typedef _Float16 h8 __attribute__((ext_vector_type(8)));
typedef float f4v __attribute__((ext_vector_type(4)));

#define SEQ 2048
#define HID 512
#define EMB 256
#define NV 32000
#define LOSCALE 2048.0f
#define INV_LOSCALE 4.8828125e-4f  // 2^-11

// ---- workspace layout (bytes) ----
#define WS_WHI 0u
#define WS_WLO (512u * 1024u)
#define WS_HG (1024u * 1024u)            // [2 buf][4 grp][2 plane][16][512] f16 = 256 KB
#define WS_FLAGS (WS_HG + 256u * 1024u)  // 16 flags @ 128B stride (4 KB region)
#define WS_PROJ (WS_FLAGS + 4u * 1024u)
#define FLAG_STRIDE 32  // u32 units = 128 B

// ---------------------------------------------------------------------------
// K0: split W_hh (fp32 [k=512][j=512]) into f16 hi + f16 lo*2^11, stored in
// MFMA B-fragment stream order. Fragment c = jtg*16+kb (jtg in [0,32), 1KB
// each); lane l holds 8 f16 = W[kb*32+(l>>4)*8+e][jtg*16+(l&15)].
// ---------------------------------------------------------------------------
__global__ void wsplit_kernel(const float* __restrict__ Whh,
                              _Float16* __restrict__ Whi,
                              _Float16* __restrict__ Wlo) {
  int gid = blockIdx.x * 256 + threadIdx.x;  // 0..32767
  int l = gid & 63, c = gid >> 6;            // c in [0,512)
  int kb = c & 15, jtg = c >> 4;
  int j = jtg * 16 + (l & 15);
  int k0 = kb * 32 + (l >> 4) * 8;
  _Float16 hi[8], lo[8];
#pragma unroll
  for (int e = 0; e < 8; ++e) {
    float v = Whh[(k0 + e) * HID + j];
    _Float16 h = (_Float16)v;
    hi[e] = h;
    lo[e] = (_Float16)((v - (float)h) * LOSCALE);
  }
  *(h8*)(Whi + (size_t)gid * 8) = *(const h8*)hi;
  *(h8*)(Wlo + (size_t)gid * 8) = *(const h8*)lo;
}

// ---------------------------------------------------------------------------
// K1: projE[v][j] = sum_d E[v][d] * W_xh[d][j] + b_xh[j]  (32000 x 512)
// ---------------------------------------------------------------------------
template <bool PF32>
__global__ __launch_bounds__(256) void proj_kernel(const float* __restrict__ E,
                                                   const float* __restrict__ Wxh,
                                                   const float* __restrict__ bxh,
                                                   void* __restrict__ projE) {
  __shared__ float El[32 * EMB];
  const int t = threadIdx.x;
  const int v0 = blockIdx.x * 32;
  {
    const float4* src = (const float4*)(E + (size_t)v0 * EMB);
    float4* dst = (float4*)El;
#pragma unroll
    for (int i = 0; i < 8; ++i) dst[t + i * 256] = src[t + i * 256];
  }
  __syncthreads();
  const int c0 = (t & 63) * 8;
  const int rg = t >> 6;
  float acc[8][8];
#pragma unroll
  for (int r = 0; r < 8; ++r)
#pragma unroll
    for (int c = 0; c < 8; ++c) acc[r][c] = 0.f;

#pragma unroll 4
  for (int d = 0; d < EMB; ++d) {
    float wv[8];
    *(float4*)&wv[0] = *(const float4*)&Wxh[d * HID + c0];
    *(float4*)&wv[4] = *(const float4*)&Wxh[d * HID + c0 + 4];
#pragma unroll
    for (int r = 0; r < 8; ++r) {
      float ev = El[(rg * 8 + r) * EMB + d];
#pragma unroll
      for (int c = 0; c < 8; ++c) acc[r][c] = fmaf(ev, wv[c], acc[r][c]);
    }
  }
  float bv[8];
  *(float4*)&bv[0] = *(const float4*)&bxh[c0];
  *(float4*)&bv[4] = *(const float4*)&bxh[c0 + 4];
#pragma unroll
  for (int r = 0; r < 8; ++r) {
    int row = v0 + rg * 8 + r;
    if (PF32) {
      float o[8];
#pragma unroll
      for (int c = 0; c < 8; ++c) o[c] = acc[r][c] + bv[c];
      *(float4*)((float*)projE + (size_t)row * HID + c0) = *(const float4*)&o[0];
      *(float4*)((float*)projE + (size_t)row * HID + c0 + 4) = *(const float4*)&o[4];
    } else {
      _Float16 o[8];
#pragma unroll
      for (int c = 0; c < 8; ++c) o[c] = (_Float16)(acc[r][c] + bv[c]);
      *(h8*)((_Float16*)projE + (size_t)row * HID + c0) = *(const h8*)o;
    }
  }
}

// ---------------------------------------------------------------------------
// K2: zero h-exchange buffers (h0 = 0) and flags. 260 KB = 16640 float4.
// Re-run every launch -> graph-replay safe.
// ---------------------------------------------------------------------------
__global__ void init_kernel(float4* __restrict__ p) {
  int gid = blockIdx.x * 256 + threadIdx.x;
  if (gid < 16640) p[gid] = (float4){0.f, 0.f, 0.f, 0.f};
}

// ---------------------------------------------------------------------------
// K3: persistent recurrence. 16 blocks = 4 batch-groups x 4 col-blocks.
// 512 threads (8 waves); wave owns 16 output cols; its W hi/lo slice lives
// in 128 VGPRs for the whole kernel (no W re-streaming). h (f16 hi + lo*2^11)
// exchanged per step through global memory, double-buffered; monotonic
// per-block flags; tid0 spins + __threadfence() (device scope: L2 wb/inv for
// cross-XCD visibility) + __syncthreads() broadcast.
// Safety: no block enters step t before ALL group flags >= t, i.e. every
// member finished step t-1 (reads included) -> double buffer is race-free.
// ---------------------------------------------------------------------------
template <bool PF32>
__global__ __launch_bounds__(512, 2) void rnn_kernel(
    const int* __restrict__ X, const _Float16* __restrict__ Whi,
    const _Float16* __restrict__ Wlo, const void* __restrict__ projE,
    const float* __restrict__ bhh, _Float16* __restrict__ hG,
    unsigned* __restrict__ flags, float* __restrict__ out) {
  const int tid = threadIdx.x;
  const int w = tid >> 6, lane = tid & 63;
  const int g = lane >> 4, li = lane & 15;
  const int grp = blockIdx.x >> 2, cb = blockIdx.x & 3;
  const int nb = grp * 16;
  const int jtg = cb * 8 + w;   // global j-tile 0..31
  const int j = jtg * 16 + li;  // global output col

  // --- W slice into registers (held for all 2048 steps) ---
  h8 Wh[16], Wl[16];
  {
    const char* wb = (const char*)Whi + ((size_t)jtg * 16 * 64 + lane) * 16;
    const char* wb2 = (const char*)Wlo + ((size_t)jtg * 16 * 64 + lane) * 16;
#pragma unroll
    for (int kb = 0; kb < 16; ++kb) {
      Wh[kb] = *(const h8*)(wb + (size_t)kb * 1024);
      Wl[kb] = *(const h8*)(wb2 + (size_t)kb * 1024);
    }
  }
  const float bias = bhh[j];
  unsigned* fl = flags + grp * 4 * FLAG_STRIDE;

  for (int t = 0; t < SEQ; ++t) {
    // xp gather — independent of the flag protocol, issued first
    float pv[4];
#pragma unroll
    for (int i = 0; i < 4; ++i) {
      int tok = X[(nb + g * 4 + i) * SEQ + t];
      if (PF32)
        pv[i] = ((const float*)projE)[(size_t)tok * HID + j];
      else
        pv[i] = (float)((const _Float16*)projE)[(size_t)tok * HID + j];
    }

    // wait until every group member published h_t (tid0 spins, then bcast)
    if (t > 0) {
      if (tid == 0) {
#pragma unroll
        for (int b = 0; b < 4; ++b) {
          unsigned spins = 0;
          while (__hip_atomic_load(fl + b * FLAG_STRIDE, __ATOMIC_RELAXED,
                                   __HIP_MEMORY_SCOPE_AGENT) < (unsigned)t) {
            if (++spins > 20000u) break;  // fail-fast instead of hang
          }
        }
        __threadfence();  // acquire side: invalidate stale L1/L2 lines
      }
      __syncthreads();
    }

    // A-fragments of h_t straight from global, 8-deep ring prefetch
    const char* hb = (const char*)hG + (size_t)((t & 1) * 4 + grp) * 32768;
    const int aoff0 = li * 1024 + g * 16;

    f4v a1 = {0.f, 0.f, 0.f, 0.f};
    f4v c1 = {0.f, 0.f, 0.f, 0.f};
    f4v c2 = {0.f, 0.f, 0.f, 0.f};
    h8 ah[8], al[8];
#pragma unroll
    for (int kb = 0; kb < 8; ++kb) {
      ah[kb] = *(const h8*)(hb + aoff0 + kb * 64);
      al[kb] = *(const h8*)(hb + 16384 + aoff0 + kb * 64);
    }
#pragma unroll
    for (int kb = 0; kb < 16; ++kb) {
      h8 ahc = ah[kb & 7], alc = al[kb & 7];
      if (kb < 8) {
        ah[kb & 7] = *(const h8*)(hb + aoff0 + (kb + 8) * 64);
        al[kb & 7] = *(const h8*)(hb + 16384 + aoff0 + (kb + 8) * 64);
      }
      a1 = __builtin_amdgcn_mfma_f32_16x16x32_f16(ahc, Wh[kb], a1, 0, 0, 0);
      c1 = __builtin_amdgcn_mfma_f32_16x16x32_f16(ahc, Wl[kb], c1, 0, 0, 0);
      c2 = __builtin_amdgcn_mfma_f32_16x16x32_f16(alc, Wh[kb], c2, 0, 0, 0);
    }

    // epilogue: v = hi + 2^-11*(cross terms) + b + xp ; tanh ; publish
    _Float16* hn =
        (_Float16*)((char*)hG + (size_t)(((t + 1) & 1) * 4 + grp) * 32768);
    const bool lastt = (t == SEQ - 1);
#pragma unroll
    for (int i = 0; i < 4; ++i) {
      int r = g * 4 + i;
      float v = a1[i] + INV_LOSCALE * (c1[i] + c2[i]) + bias + pv[i];
      float e2 = __expf(2.0f * v);
      float th = 1.0f - 2.0f / (e2 + 1.0f);
      _Float16 hh = (_Float16)th;
      _Float16 hl = (_Float16)((th - (float)hh) * LOSCALE);
      hn[(size_t)r * 512 + j] = hh;
      hn[8192 + (size_t)r * 512 + j] = hl;  // lo plane (+16 KB)
      if (lastt) out[(nb + r) * HID + j] = th;
    }
    __syncthreads();  // compiler drains vmcnt(0) per wave before s_barrier
    if (tid == 0) {
      __threadfence();  // release side: write back block's h stores
      __hip_atomic_store(fl + cb * FLAG_STRIDE, (unsigned)(t + 1),
                         __ATOMIC_RELAXED, __HIP_MEMORY_SCOPE_AGENT);
    }
  }
}

// ---------------------------------------------------------------------------
extern "C" void kernel_launch(void* const* d_in, const int* in_sizes, int n_in,
                              void* d_out, int out_size, void* d_ws,
                              size_t ws_size, hipStream_t stream) {
  const int* X = (const int*)d_in[0];
  const float* E = (const float*)d_in[1];
  const float* Whh = (const float*)d_in[2];
  const float* bhh = (const float*)d_in[3];
  const float* Wxh = (const float*)d_in[4];
  const float* bxh = (const float*)d_in[5];
  float* out = (float*)d_out;

  char* ws = (char*)d_ws;
  _Float16* Whi = (_Float16*)(ws + WS_WHI);
  _Float16* Wlo = (_Float16*)(ws + WS_WLO);
  _Float16* hG = (_Float16*)(ws + WS_HG);
  unsigned* flags = (unsigned*)(ws + WS_FLAGS);
  void* projE = (void*)(ws + WS_PROJ);
  const bool pf32 = ws_size >= (size_t)WS_PROJ + (size_t)NV * HID * sizeof(float);

  wsplit_kernel<<<128, 256, 0, stream>>>(Whh, Whi, Wlo);
  init_kernel<<<65, 256, 0, stream>>>((float4*)(ws + WS_HG));
  if (pf32) {
    proj_kernel<true><<<NV / 32, 256, 0, stream>>>(E, Wxh, bxh, projE);
    rnn_kernel<true><<<16, 512, 0, stream>>>(X, Whi, Wlo, projE, bhh, hG, flags, out);
  } else {
    proj_kernel<false><<<NV / 32, 256, 0, stream>>>(E, Wxh, bxh, projE);
    rnn_kernel<false><<<16, 512, 0, stream>>>(X, Whi, Wlo, projE, bhh, hG, flags, out);
  }
}

// Round 6
// 7521.655 us; speedup vs baseline: 6.6698x; 2.7901x over previous
//
#include <hip/hip_runtime.h>

typedef _Float16 h8 __attribute__((ext_vector_type(8)));
typedef float f4v __attribute__((ext_vector_type(4)));
typedef unsigned int u32;
typedef unsigned long long u64;
typedef u32 u32x4 __attribute__((ext_vector_type(4)));

#define SEQ 2048
#define HID 512
#define EMB 256
#define NV 32000
#define LOSCALE 2048.0f
#define INV_LOSCALE 4.8828125e-4f  // 2^-11

// ---- workspace layout (bytes) ----
#define WS_WHI 0u
#define WS_WLO (512u * 1024u)
#define WS_HG (1024u * 1024u)            // packed h: [2 buf][4 grp][16 kb][2 c][64 lane][4] u32 = 256 KB
#define WS_FLAGS (WS_HG + 256u * 1024u)  // 16 flags @ 128B stride (4 KB region)
#define WS_PROJ (WS_FLAGS + 4u * 1024u)
#define FLAG_STRIDE 32  // u32 units = 128 B

// ---------------------------------------------------------------------------
// K0: split W_hh (fp32 [k=512][j=512]) into f16 hi + f16 lo*2^11, stored in
// MFMA B-fragment stream order. Fragment c = jtg*16+kb (jtg in [0,32), 1KB
// each); lane l holds 8 f16 = W[kb*32+(l>>4)*8+e][jtg*16+(l&15)].
// ---------------------------------------------------------------------------
__global__ void wsplit_kernel(const float* __restrict__ Whh,
                              _Float16* __restrict__ Whi,
                              _Float16* __restrict__ Wlo) {
  int gid = blockIdx.x * 256 + threadIdx.x;  // 0..32767
  int l = gid & 63, c = gid >> 6;            // c in [0,512)
  int kb = c & 15, jtg = c >> 4;
  int j = jtg * 16 + (l & 15);
  int k0 = kb * 32 + (l >> 4) * 8;
  _Float16 hi[8], lo[8];
#pragma unroll
  for (int e = 0; e < 8; ++e) {
    float v = Whh[(k0 + e) * HID + j];
    _Float16 h = (_Float16)v;
    hi[e] = h;
    lo[e] = (_Float16)((v - (float)h) * LOSCALE);
  }
  *(h8*)(Whi + (size_t)gid * 8) = *(const h8*)hi;
  *(h8*)(Wlo + (size_t)gid * 8) = *(const h8*)lo;
}

// ---------------------------------------------------------------------------
// K1: projE[v][j] = sum_d E[v][d] * W_xh[d][j] + b_xh[j]  (32000 x 512)
// ---------------------------------------------------------------------------
template <bool PF32>
__global__ __launch_bounds__(256) void proj_kernel(const float* __restrict__ E,
                                                   const float* __restrict__ Wxh,
                                                   const float* __restrict__ bxh,
                                                   void* __restrict__ projE) {
  __shared__ float El[32 * EMB];
  const int t = threadIdx.x;
  const int v0 = blockIdx.x * 32;
  {
    const float4* src = (const float4*)(E + (size_t)v0 * EMB);
    float4* dst = (float4*)El;
#pragma unroll
    for (int i = 0; i < 8; ++i) dst[t + i * 256] = src[t + i * 256];
  }
  __syncthreads();
  const int c0 = (t & 63) * 8;
  const int rg = t >> 6;
  float acc[8][8];
#pragma unroll
  for (int r = 0; r < 8; ++r)
#pragma unroll
    for (int c = 0; c < 8; ++c) acc[r][c] = 0.f;

#pragma unroll 4
  for (int d = 0; d < EMB; ++d) {
    float wv[8];
    *(float4*)&wv[0] = *(const float4*)&Wxh[d * HID + c0];
    *(float4*)&wv[4] = *(const float4*)&Wxh[d * HID + c0 + 4];
#pragma unroll
    for (int r = 0; r < 8; ++r) {
      float ev = El[(rg * 8 + r) * EMB + d];
#pragma unroll
      for (int c = 0; c < 8; ++c) acc[r][c] = fmaf(ev, wv[c], acc[r][c]);
    }
  }
  float bv[8];
  *(float4*)&bv[0] = *(const float4*)&bxh[c0];
  *(float4*)&bv[4] = *(const float4*)&bxh[c0 + 4];
#pragma unroll
  for (int r = 0; r < 8; ++r) {
    int row = v0 + rg * 8 + r;
    if (PF32) {
      float o[8];
#pragma unroll
      for (int c = 0; c < 8; ++c) o[c] = acc[r][c] + bv[c];
      *(float4*)((float*)projE + (size_t)row * HID + c0) = *(const float4*)&o[0];
      *(float4*)((float*)projE + (size_t)row * HID + c0 + 4) = *(const float4*)&o[4];
    } else {
      _Float16 o[8];
#pragma unroll
      for (int c = 0; c < 8; ++c) o[c] = (_Float16)(acc[r][c] + bv[c]);
      *(h8*)((_Float16*)projE + (size_t)row * HID + c0) = *(const h8*)o;
    }
  }
}

// ---------------------------------------------------------------------------
// K2: zero h-exchange buffers (h0 = 0, packed u32 of (0,0)=0) and flags.
// 260 KB = 16640 float4. Re-run every launch -> graph-replay safe.
// ---------------------------------------------------------------------------
__global__ void init_kernel(float4* __restrict__ p) {
  int gid = blockIdx.x * 256 + threadIdx.x;
  if (gid < 16640) p[gid] = (float4){0.f, 0.f, 0.f, 0.f};
}

// ---------------------------------------------------------------------------
// K3: persistent recurrence. 16 blocks = 4 batch-groups x 4 col-blocks,
// 512 threads (8 waves). Wave owns 16 output cols; W hi/lo slice resident in
// 128 regs. h exchanged FENCE-FREE through a packed-u32 global buffer:
//   publish: per-element agent-scope relaxed atomic stores (sc1 write-through
//            to the coherence point); __syncthreads drains vmcnt -> visible;
//            tid0 then sets this block's flag (agent atomic).
//   consume: lanes 0-3 of every wave poll the 4 group flags in parallel;
//            block then cooperatively stages its group's 32 KB via sc1 u64
//            loads into LDS (fragment order, conflict-free ds_read_b128).
// No threadfence => no L2 writeback/invalidate; W & projE stay L2-warm.
// Global layout (u32 idx): [buf][grp][kb 16][c 2][lane 64][x 4]
//   value(kb,c,lane,x) = pack(h[lane&15][kb*32+(lane>>4)*8+c*4+x]) hi|lo<<16
// ---------------------------------------------------------------------------
template <bool PF32>
__global__ __launch_bounds__(512, 2) void rnn_kernel(
    const int* __restrict__ X, const _Float16* __restrict__ Whi,
    const _Float16* __restrict__ Wlo, const void* __restrict__ projE,
    const float* __restrict__ bhh, u32* __restrict__ hX,
    u32* __restrict__ flags, float* __restrict__ out) {
  __shared__ u32 hs[8192];  // 32 KB staged h, [kb][c][lane][4]
  const int tid = threadIdx.x;
  const int w = tid >> 6, lane = tid & 63;
  const int g = lane >> 4, li = lane & 15;
  const int grp = blockIdx.x >> 2, cb = blockIdx.x & 3;
  const int nb = grp * 16;
  const int jtg = cb * 8 + w;   // global j-tile 0..31
  const int j = jtg * 16 + li;  // global output col

  // --- W slice into registers (held for all 2048 steps) ---
  h8 Wh[16], Wl[16];
  {
    const char* wb = (const char*)Whi + ((size_t)jtg * 16 * 64 + lane) * 16;
    const char* wb2 = (const char*)Wlo + ((size_t)jtg * 16 * 64 + lane) * 16;
#pragma unroll
    for (int kb = 0; kb < 16; ++kb) {
      Wh[kb] = *(const h8*)(wb + (size_t)kb * 1024);
      Wl[kb] = *(const h8*)(wb2 + (size_t)kb * 1024);
    }
  }
  const float bias = bhh[j];
  u32* fl = flags + grp * 4 * FLAG_STRIDE;

  // publish index (grp-local u32 idx): element (row r=g*4+i, col j)
  const int gq = ((jtg & 1) << 1) | (li >> 3);
  const int pubbase = (jtg >> 1) * 512 + ((li >> 2) & 1) * 256 +
                      (gq * 16 + g * 4) * 4 + (li & 3);
  u32* const hgrp = hX + grp * 8192;

  for (int t = 0; t < SEQ; ++t) {
    // xp gather — independent of the protocol, issue first
    float pv[4];
#pragma unroll
    for (int i = 0; i < 4; ++i) {
      int tok = X[(nb + g * 4 + i) * SEQ + t];
      if (PF32)
        pv[i] = ((const float*)projE)[(size_t)tok * HID + j];
      else
        pv[i] = (float)((const _Float16*)projE)[(size_t)tok * HID + j];
    }

    // lane-parallel spin: lane b (<4) of EVERY wave polls group flag b
    if (t > 0 && lane < 4) {
      u32 spins = 0;
      while (__hip_atomic_load(fl + lane * FLAG_STRIDE, __ATOMIC_RELAXED,
                               __HIP_MEMORY_SCOPE_AGENT) < (u32)t) {
        if (++spins > 10000u) break;  // fail-fast instead of hang
      }
    }

    // cooperative stage: 32 KB group-h from coherence point -> LDS
    {
      const u32* src = hgrp + (t & 1) * 32768;
      u64 v[4][2];
#pragma unroll
      for (int q = 0; q < 4; ++q) {
        int idx = tid * 4 + q * 2048;
        v[q][0] = __hip_atomic_load((const u64*)(src + idx), __ATOMIC_RELAXED,
                                    __HIP_MEMORY_SCOPE_AGENT);
        v[q][1] = __hip_atomic_load((const u64*)(src + idx + 2),
                                    __ATOMIC_RELAXED, __HIP_MEMORY_SCOPE_AGENT);
      }
#pragma unroll
      for (int q = 0; q < 4; ++q) {
        u32x4 d;
        d[0] = (u32)v[q][0]; d[1] = (u32)(v[q][0] >> 32);
        d[2] = (u32)v[q][1]; d[3] = (u32)(v[q][1] >> 32);
        *(u32x4*)(hs + tid * 4 + q * 2048) = d;
      }
    }
    __syncthreads();

    // compute: unpack fragments from LDS, 3-term split MFMA
    f4v a1 = {0.f, 0.f, 0.f, 0.f};
    f4v c1 = {0.f, 0.f, 0.f, 0.f};
    f4v c2 = {0.f, 0.f, 0.f, 0.f};
#pragma unroll
    for (int kb = 0; kb < 16; ++kb) {
      u32x4 p0 = *(const u32x4*)(hs + kb * 512 + lane * 4);        // e 0..3
      u32x4 p1 = *(const u32x4*)(hs + kb * 512 + 256 + lane * 4);  // e 4..7
      u32 hiw[4], low[4];
      hiw[0] = (p0[0] & 0xFFFFu) | (p0[1] << 16);
      hiw[1] = (p0[2] & 0xFFFFu) | (p0[3] << 16);
      hiw[2] = (p1[0] & 0xFFFFu) | (p1[1] << 16);
      hiw[3] = (p1[2] & 0xFFFFu) | (p1[3] << 16);
      low[0] = (p0[0] >> 16) | (p0[1] & 0xFFFF0000u);
      low[1] = (p0[2] >> 16) | (p0[3] & 0xFFFF0000u);
      low[2] = (p1[0] >> 16) | (p1[1] & 0xFFFF0000u);
      low[3] = (p1[2] >> 16) | (p1[3] & 0xFFFF0000u);
      h8 ahc = *(const h8*)hiw;
      h8 alc = *(const h8*)low;
      a1 = __builtin_amdgcn_mfma_f32_16x16x32_f16(ahc, Wh[kb], a1, 0, 0, 0);
      c1 = __builtin_amdgcn_mfma_f32_16x16x32_f16(ahc, Wl[kb], c1, 0, 0, 0);
      c2 = __builtin_amdgcn_mfma_f32_16x16x32_f16(alc, Wh[kb], c2, 0, 0, 0);
    }

    // epilogue: v = hi + 2^-11*(cross) + b + xp ; tanh ; publish write-through
    u32* const hn = hgrp + ((t + 1) & 1) * 32768;
    const bool lastt = (t == SEQ - 1);
#pragma unroll
    for (int i = 0; i < 4; ++i) {
      float v = a1[i] + INV_LOSCALE * (c1[i] + c2[i]) + bias + pv[i];
      float e2 = __expf(2.0f * v);
      float th = 1.0f - 2.0f / (e2 + 1.0f);
      _Float16 hh = (_Float16)th;
      _Float16 hl = (_Float16)((th - (float)hh) * LOSCALE);
      u32 packed = (u32)__builtin_bit_cast(unsigned short, hh) |
                   ((u32)__builtin_bit_cast(unsigned short, hl) << 16);
      __hip_atomic_store(hn + pubbase + i * 4, packed, __ATOMIC_RELAXED,
                         __HIP_MEMORY_SCOPE_AGENT);
      if (lastt) out[(nb + g * 4 + i) * HID + j] = th;
    }
    __syncthreads();  // drains vmcnt per wave -> all sc1 stores visible
    if (tid == 0) {
      __hip_atomic_store(fl + cb * FLAG_STRIDE, (u32)(t + 1), __ATOMIC_RELAXED,
                         __HIP_MEMORY_SCOPE_AGENT);
    }
  }
}

// ---------------------------------------------------------------------------
extern "C" void kernel_launch(void* const* d_in, const int* in_sizes, int n_in,
                              void* d_out, int out_size, void* d_ws,
                              size_t ws_size, hipStream_t stream) {
  const int* X = (const int*)d_in[0];
  const float* E = (const float*)d_in[1];
  const float* Whh = (const float*)d_in[2];
  const float* bhh = (const float*)d_in[3];
  const float* Wxh = (const float*)d_in[4];
  const float* bxh = (const float*)d_in[5];
  float* out = (float*)d_out;

  char* ws = (char*)d_ws;
  _Float16* Whi = (_Float16*)(ws + WS_WHI);
  _Float16* Wlo = (_Float16*)(ws + WS_WLO);
  u32* hX = (u32*)(ws + WS_HG);
  u32* flags = (u32*)(ws + WS_FLAGS);
  void* projE = (void*)(ws + WS_PROJ);
  const bool pf32 = ws_size >= (size_t)WS_PROJ + (size_t)NV * HID * sizeof(float);

  wsplit_kernel<<<128, 256, 0, stream>>>(Whh, Whi, Wlo);
  init_kernel<<<65, 256, 0, stream>>>((float4*)(ws + WS_HG));
  if (pf32) {
    proj_kernel<true><<<NV / 32, 256, 0, stream>>>(E, Wxh, bxh, projE);
    rnn_kernel<true><<<16, 512, 0, stream>>>(X, Whi, Wlo, projE, bhh, hX, flags, out);
  } else {
    proj_kernel<false><<<NV / 32, 256, 0, stream>>>(E, Wxh, bxh, projE);
    rnn_kernel<false><<<16, 512, 0, stream>>>(X, Whi, Wlo, projE, bhh, hX, flags, out);
  }
}

// Round 7
// 6247.523 us; speedup vs baseline: 8.0300x; 1.2039x over previous
//
#include <hip/hip_runtime.h>

typedef _Float16 h8 __attribute__((ext_vector_type(8)));
typedef float f4v __attribute__((ext_vector_type(4)));
typedef unsigned int u32;
typedef unsigned long long u64;
typedef u32 u32x4 __attribute__((ext_vector_type(4)));

#define SEQ 2048
#define HID 512
#define EMB 256
#define NV 32000
#define LOSCALE 2048.0f
#define INV_LOSCALE 4.8828125e-4f  // 2^-11

// ---- workspace layout (bytes) ----
#define WS_WHI 0u
#define WS_WLO (512u * 1024u)
#define WS_HG (1024u * 1024u)            // h: [2 buf][4 grp][2 plane][4096 u32] = 256 KB
#define WS_FLAGS (WS_HG + 256u * 1024u)  // 16 flags @ 128B stride (4 KB region)
#define WS_PROJ (WS_FLAGS + 4u * 1024u)
#define FLAG_STRIDE 32  // u32 units = 128 B

// ---------------------------------------------------------------------------
// K0: split W_hh (fp32 [k=512][j=512]) into f16 hi + f16 lo*2^11, stored in
// MFMA B-fragment stream order. Fragment c = jtg*16+kb (jtg in [0,32), 1KB
// each); lane l holds 8 f16 = W[kb*32+(l>>4)*8+e][jtg*16+(l&15)].
// ---------------------------------------------------------------------------
__global__ void wsplit_kernel(const float* __restrict__ Whh,
                              _Float16* __restrict__ Whi,
                              _Float16* __restrict__ Wlo) {
  int gid = blockIdx.x * 256 + threadIdx.x;  // 0..32767
  int l = gid & 63, c = gid >> 6;            // c in [0,512)
  int kb = c & 15, jtg = c >> 4;
  int j = jtg * 16 + (l & 15);
  int k0 = kb * 32 + (l >> 4) * 8;
  _Float16 hi[8], lo[8];
#pragma unroll
  for (int e = 0; e < 8; ++e) {
    float v = Whh[(k0 + e) * HID + j];
    _Float16 h = (_Float16)v;
    hi[e] = h;
    lo[e] = (_Float16)((v - (float)h) * LOSCALE);
  }
  *(h8*)(Whi + (size_t)gid * 8) = *(const h8*)hi;
  *(h8*)(Wlo + (size_t)gid * 8) = *(const h8*)lo;
}

// ---------------------------------------------------------------------------
// K1: projE[v][j] = sum_d E[v][d] * W_xh[d][j] + b_xh[j]  (32000 x 512)
// ---------------------------------------------------------------------------
template <bool PF32>
__global__ __launch_bounds__(256) void proj_kernel(const float* __restrict__ E,
                                                   const float* __restrict__ Wxh,
                                                   const float* __restrict__ bxh,
                                                   void* __restrict__ projE) {
  __shared__ float El[32 * EMB];
  const int t = threadIdx.x;
  const int v0 = blockIdx.x * 32;
  {
    const float4* src = (const float4*)(E + (size_t)v0 * EMB);
    float4* dst = (float4*)El;
#pragma unroll
    for (int i = 0; i < 8; ++i) dst[t + i * 256] = src[t + i * 256];
  }
  __syncthreads();
  const int c0 = (t & 63) * 8;
  const int rg = t >> 6;
  float acc[8][8];
#pragma unroll
  for (int r = 0; r < 8; ++r)
#pragma unroll
    for (int c = 0; c < 8; ++c) acc[r][c] = 0.f;

#pragma unroll 4
  for (int d = 0; d < EMB; ++d) {
    float wv[8];
    *(float4*)&wv[0] = *(const float4*)&Wxh[d * HID + c0];
    *(float4*)&wv[4] = *(const float4*)&Wxh[d * HID + c0 + 4];
#pragma unroll
    for (int r = 0; r < 8; ++r) {
      float ev = El[(rg * 8 + r) * EMB + d];
#pragma unroll
      for (int c = 0; c < 8; ++c) acc[r][c] = fmaf(ev, wv[c], acc[r][c]);
    }
  }
  float bv[8];
  *(float4*)&bv[0] = *(const float4*)&bxh[c0];
  *(float4*)&bv[4] = *(const float4*)&bxh[c0 + 4];
#pragma unroll
  for (int r = 0; r < 8; ++r) {
    int row = v0 + rg * 8 + r;
    if (PF32) {
      float o[8];
#pragma unroll
      for (int c = 0; c < 8; ++c) o[c] = acc[r][c] + bv[c];
      *(float4*)((float*)projE + (size_t)row * HID + c0) = *(const float4*)&o[0];
      *(float4*)((float*)projE + (size_t)row * HID + c0 + 4) = *(const float4*)&o[4];
    } else {
      _Float16 o[8];
#pragma unroll
      for (int c = 0; c < 8; ++c) o[c] = (_Float16)(acc[r][c] + bv[c]);
      *(h8*)((_Float16*)projE + (size_t)row * HID + c0) = *(const h8*)o;
    }
  }
}

// ---------------------------------------------------------------------------
// K2: zero h-exchange buffers (h0 = 0) and flags. 260 KB = 16640 float4.
// ---------------------------------------------------------------------------
__global__ void init_kernel(float4* __restrict__ p) {
  int gid = blockIdx.x * 256 + threadIdx.x;
  if (gid < 16640) p[gid] = (float4){0.f, 0.f, 0.f, 0.f};
}

// ---------------------------------------------------------------------------
// K3: persistent recurrence. 16 blocks = 4 batch-groups x 4 col-blocks,
// 512 threads (8 waves). Wave owns 16 output cols; W hi/lo slice is pinned in
// 128 VGPRs via inline-asm laundering (compiler cannot rematerialize).
// h exchanged fence-free through packed-u32 global planes (agent-scope sc1
// write-through stores / loads); planes hold READY MFMA A-fragments:
//   plane P word (kb, lane, m) = pack(hP[lane&15][kb*32+(lane>>4)*8+2m],
//                                     hP[same][ ... +2m+1])
// so consume = linear memcpy to LDS + ds_read_b128, zero unpack VALU.
// Publishers pair adjacent-j lanes with one shfl_xor(1); even li writes the
// hi-plane word, odd li the lo-plane word (bijective, no collisions).
// Flags: monotonic per-block counters, lane-parallel polling (lanes 0-3 of
// every wave), __syncthreads vmcnt-drain makes stores visible before flag.
// ---------------------------------------------------------------------------
template <bool PF32>
__global__ __launch_bounds__(512, 2) void rnn_kernel(
    const int* __restrict__ X, const _Float16* __restrict__ Whi,
    const _Float16* __restrict__ Wlo, const void* __restrict__ projE,
    const float* __restrict__ bhh, u32* __restrict__ hX,
    u32* __restrict__ flags, float* __restrict__ out) {
  __shared__ u32 hs[8192];  // 32 KB staged h: [plane 2][kb 16][lane 64][m 4]
  const int tid = threadIdx.x;
  const int w = tid >> 6, lane = tid & 63;
  const int g = lane >> 4, li = lane & 15;
  const int grp = blockIdx.x >> 2, cb = blockIdx.x & 3;
  const int nb = grp * 16;
  const int jtg = cb * 8 + w;   // global j-tile 0..31
  const int j = jtg * 16 + li;  // global output col

  // --- W slice into registers, laundered so it STAYS in registers ---
  h8 Wh[16], Wl[16];
  {
    const char* wb = (const char*)Whi + ((size_t)jtg * 16 * 64 + lane) * 16;
    const char* wb2 = (const char*)Wlo + ((size_t)jtg * 16 * 64 + lane) * 16;
#pragma unroll
    for (int kb = 0; kb < 16; ++kb) {
      Wh[kb] = *(const h8*)(wb + (size_t)kb * 1024);
      Wl[kb] = *(const h8*)(wb2 + (size_t)kb * 1024);
    }
#pragma unroll
    for (int kb = 0; kb < 16; ++kb) {
      f4v th = __builtin_bit_cast(f4v, Wh[kb]);
      f4v tl = __builtin_bit_cast(f4v, Wl[kb]);
      asm volatile("" : "+v"(th), "+v"(tl));
      Wh[kb] = __builtin_bit_cast(h8, th);
      Wl[kb] = __builtin_bit_cast(h8, tl);
    }
  }
  const float bias = bhh[j];
  u32* fl = flags + grp * 4 * FLAG_STRIDE;

  // publish word index (u32, within this grp's 8192-u32 block)
  const int hi2 = ((jtg & 1) << 1) | (li >> 3);
  const int pub0 = (li & 1) * 4096 + (jtg >> 1) * 256 + (hi2 << 6) + g * 16 +
                   ((li & 7) >> 1);
  u32* const hgrp = hX + grp * 8192;
  const bool oddli = (li & 1) != 0;

  const int* Xr[4];
#pragma unroll
  for (int i = 0; i < 4; ++i) Xr[i] = X + (size_t)(nb + g * 4 + i) * SEQ;

  for (int t = 0; t < SEQ; ++t) {
    // xp gather — independent of the protocol, issue first
    float pv[4];
#pragma unroll
    for (int i = 0; i < 4; ++i) {
      int tok = Xr[i][t];
      if (PF32)
        pv[i] = ((const float*)projE)[(size_t)tok * HID + j];
      else
        pv[i] = (float)((const _Float16*)projE)[(size_t)tok * HID + j];
    }

    // lane-parallel spin: lane b (<4) of EVERY wave polls group flag b
    if (t > 0 && lane < 4) {
      u32 spins = 0;
      while (__hip_atomic_load(fl + lane * FLAG_STRIDE, __ATOMIC_RELAXED,
                               __HIP_MEMORY_SCOPE_AGENT) < (u32)t) {
        if (++spins > 10000u) break;  // fail-fast instead of hang
      }
    }

    // cooperative stage: 32 KB group-h, straight memcpy coherence point->LDS
    {
      const u32* src = hgrp + (t & 1) * 32768;
      u64 v[4][2];
#pragma unroll
      for (int q = 0; q < 4; ++q) {
        int idx = tid * 4 + q * 2048;
        v[q][0] = __hip_atomic_load((const u64*)(src + idx), __ATOMIC_RELAXED,
                                    __HIP_MEMORY_SCOPE_AGENT);
        v[q][1] = __hip_atomic_load((const u64*)(src + idx + 2),
                                    __ATOMIC_RELAXED, __HIP_MEMORY_SCOPE_AGENT);
      }
#pragma unroll
      for (int q = 0; q < 4; ++q) {
        u32x4 d;
        d[0] = (u32)v[q][0]; d[1] = (u32)(v[q][0] >> 32);
        d[2] = (u32)v[q][1]; d[3] = (u32)(v[q][1] >> 32);
        *(u32x4*)(hs + tid * 4 + q * 2048) = d;
      }
    }
    __syncthreads();

    // compute: fragments are ready in LDS — 2 ds_read_b128 + 3 MFMA per kb
    f4v a1 = {0.f, 0.f, 0.f, 0.f};
    f4v c1 = {0.f, 0.f, 0.f, 0.f};
    f4v c2 = {0.f, 0.f, 0.f, 0.f};
    const u32* hb_hi = hs + lane * 4;
    const u32* hb_lo = hs + 4096 + lane * 4;
#pragma unroll
    for (int kb = 0; kb < 16; ++kb) {
      h8 ahc = *(const h8*)(hb_hi + kb * 256);
      h8 alc = *(const h8*)(hb_lo + kb * 256);
      a1 = __builtin_amdgcn_mfma_f32_16x16x32_f16(ahc, Wh[kb], a1, 0, 0, 0);
      c1 = __builtin_amdgcn_mfma_f32_16x16x32_f16(ahc, Wl[kb], c1, 0, 0, 0);
      c2 = __builtin_amdgcn_mfma_f32_16x16x32_f16(alc, Wh[kb], c2, 0, 0, 0);
    }

    // epilogue: tanh; pair lanes; publish plane-separated fragment words
    u32* const hn = hgrp + ((t + 1) & 1) * 32768;
    const bool lastt = (t == SEQ - 1);
#pragma unroll
    for (int i = 0; i < 4; ++i) {
      float v = a1[i] + INV_LOSCALE * (c1[i] + c2[i]) + bias + pv[i];
      float e2 = __expf(2.0f * v);
      float th = 1.0f - 2.0f / (e2 + 1.0f);
      _Float16 hh = (_Float16)th;
      _Float16 hl = (_Float16)((th - (float)hh) * LOSCALE);
      u32 pk = (u32)__builtin_bit_cast(unsigned short, hh) |
               ((u32)__builtin_bit_cast(unsigned short, hl) << 16);
      u32 nbv = (u32)__shfl_xor((int)pk, 1, 64);
      // even li -> hi-plane word (self low half); odd li -> lo-plane word
      u32 word = oddli ? ((nbv >> 16) | (pk & 0xFFFF0000u))
                       : ((pk & 0xFFFFu) | (nbv << 16));
      __hip_atomic_store(hn + pub0 + i * 4, word, __ATOMIC_RELAXED,
                         __HIP_MEMORY_SCOPE_AGENT);
      if (lastt) out[(nb + g * 4 + i) * HID + j] = th;
    }
    __syncthreads();  // drains vmcnt per wave -> all sc1 stores visible
    if (tid == 0) {
      __hip_atomic_store(fl + cb * FLAG_STRIDE, (u32)(t + 1), __ATOMIC_RELAXED,
                         __HIP_MEMORY_SCOPE_AGENT);
    }
  }
}

// ---------------------------------------------------------------------------
extern "C" void kernel_launch(void* const* d_in, const int* in_sizes, int n_in,
                              void* d_out, int out_size, void* d_ws,
                              size_t ws_size, hipStream_t stream) {
  const int* X = (const int*)d_in[0];
  const float* E = (const float*)d_in[1];
  const float* Whh = (const float*)d_in[2];
  const float* bhh = (const float*)d_in[3];
  const float* Wxh = (const float*)d_in[4];
  const float* bxh = (const float*)d_in[5];
  float* out = (float*)d_out;

  char* ws = (char*)d_ws;
  _Float16* Whi = (_Float16*)(ws + WS_WHI);
  _Float16* Wlo = (_Float16*)(ws + WS_WLO);
  u32* hX = (u32*)(ws + WS_HG);
  u32* flags = (u32*)(ws + WS_FLAGS);
  void* projE = (void*)(ws + WS_PROJ);
  const bool pf32 = ws_size >= (size_t)WS_PROJ + (size_t)NV * HID * sizeof(float);

  wsplit_kernel<<<128, 256, 0, stream>>>(Whh, Whi, Wlo);
  init_kernel<<<65, 256, 0, stream>>>((float4*)(ws + WS_HG));
  if (pf32) {
    proj_kernel<true><<<NV / 32, 256, 0, stream>>>(E, Wxh, bxh, projE);
    rnn_kernel<true><<<16, 512, 0, stream>>>(X, Whi, Wlo, projE, bhh, hX, flags, out);
  } else {
    proj_kernel<false><<<NV / 32, 256, 0, stream>>>(E, Wxh, bxh, projE);
    rnn_kernel<false><<<16, 512, 0, stream>>>(X, Whi, Wlo, projE, bhh, hX, flags, out);
  }
}